// Round 1
// 215.621 us; speedup vs baseline: 1.0545x; 1.0545x over previous
//
#include <hip/hip_runtime.h>
#include <hip/hip_bf16.h>

// GCN 2-layer: h1 = relu(Ahat @ (x@W1) + b1); out = Ahat @ (h1@W2) + b2
// Ahat = D^-1/2 (A + I) D^-1/2.
//
// Pipeline (zero global atomics):
//   k_hist/k_scan_cols/k_scan_totals/k_scatter: deterministic bucket partition
//     (bucket = dst>>6) via per-block LDS histograms.
//   k_csr: per bucket -> per-node PAIR-ALIGNED, SENTINEL-PADDED src lists
//     (ssrcp; sentinel src = n -> zero row of hs), qbeg/qcnt, dinv; zeroes
//     hs row n and writes guard pair ssrcp[0..1] = {n,n}.
//   k_gemm: register-tiled 64x64; epilogue writes hs = bf16(dinv * (X@W)).
//   k_agg: wave per node; OCTA-edge dwordx4 gathers (8 edge-rows / instr),
//     8-pair batches, NO masks (sentinels add 0), scalar index loads; tail
//     batch pads via SALU cselect to the guard pair.
// R3: never funnel E atomics into few global addresses.
// R4: agg needs a huge grid + deep MLP, not per-bucket LDS atomics.
// R5: s_barrier is workgroup-scope; 64-wide scan in wave 0 uses shfl.
// R6: bf16 rows halve gather bytes. R7/R10: pack as many edges per gather
//     instr as the row layout allows (was 2 via dword; now 8 via dwordx4 ->
//     4x fewer VMEM instrs, ~2x less select/addr VALU, same bytes).
// R8: masked full-width batches beat scalar remainder loops.
// R9: index-clamp killed s_load vectorization; live-masks were >half the VALU
//     -> sentinel padding removes both.
// R10: hist/scatter/csr ran at 1 block/CU/256thr = 1 wave/SIMD (pure latency
//     chains with no hiding) -> 1024-thread blocks, 4x occupancy, same layout.
//     Batch granularity 16->8 pairs: mean padded degree ~16.5 pairs made the
//     guard-tail ~1.5x of real work; 8-pair batches cut that to ~1.24x.

#define NB_MAX 1024  // max buckets (n <= 65535 for ushort src packing)

__device__ inline unsigned short f2bf(float f) {      // RNE fp32 -> bf16
    unsigned u = __builtin_bit_cast(unsigned, f);
    return (unsigned short)((u + 0x7FFFu + ((u >> 16) & 1u)) >> 16);
}
__device__ inline float blo(unsigned u) {             // low bf16 -> fp32
    return __builtin_bit_cast(float, u << 16);
}
__device__ inline float bhi(unsigned u) {             // high bf16 -> fp32
    return __builtin_bit_cast(float, u & 0xFFFF0000u);
}

// ---- 1. per-block bucket histogram (256 blocks x 1024 thr = 4 waves/SIMD) -

__global__ __launch_bounds__(1024) void k_hist(const int* __restrict__ ei, int E,
                                               int nb, int chunk,
                                               int* __restrict__ histT) {
    __shared__ int h[NB_MAX];
    for (int i = threadIdx.x; i < nb; i += 1024) h[i] = 0;
    __syncthreads();
    int e0 = blockIdx.x * chunk, e1 = min(E, e0 + chunk);
    for (int e = e0 + threadIdx.x; e < e1; e += 1024)
        atomicAdd(&h[ei[E + e] >> 6], 1);          // LDS atomic
    __syncthreads();
    for (int b = threadIdx.x; b < nb; b += 1024)
        histT[b * 256 + blockIdx.x] = h[b];        // [bucket][block]
}

// ---- 2. scan each bucket's 256 per-block counts ---------------------------

__global__ __launch_bounds__(256) void k_scan_cols(int* __restrict__ histT,
                                                   int* __restrict__ total) {
    __shared__ int sm[256];
    int b = blockIdx.x, t = threadIdx.x;
    int v = histT[b * 256 + t];
    sm[t] = v;
    __syncthreads();
    for (int off = 1; off < 256; off <<= 1) {
        int u = (t >= off) ? sm[t - off] : 0;
        __syncthreads();
        sm[t] += u;
        __syncthreads();
    }
    histT[b * 256 + t] = sm[t] - v;                // exclusive within bucket
    if (t == 255) total[b] = sm[255];
}

// ---- 3. scan bucket totals -> bucket bases --------------------------------

__global__ __launch_bounds__(1024) void k_scan_totals(const int* __restrict__ total,
                                                      int* __restrict__ base, int nb) {
    __shared__ int sm[1024];
    int t = threadIdx.x;
    int v = (t < nb) ? total[t] : 0;
    sm[t] = v;
    __syncthreads();
    for (int off = 1; off < 1024; off <<= 1) {
        int u = (t >= off) ? sm[t - off] : 0;
        __syncthreads();
        sm[t] += u;
        __syncthreads();
    }
    if (t < nb) base[t] = sm[t] - v;               // exclusive
    if (t == nb - 1) base[nb] = sm[t];             // total E
}

// ---- 4. scatter packed edges into bucket-grouped order --------------------

__global__ __launch_bounds__(1024) void k_scatter(const int* __restrict__ ei, int E,
                                                  int nb, int chunk,
                                                  const int* __restrict__ histT,
                                                  const int* __restrict__ base,
                                                  unsigned* __restrict__ packed) {
    __shared__ int cur[NB_MAX];
    for (int b = threadIdx.x; b < nb; b += 1024)
        cur[b] = base[b] + histT[b * 256 + blockIdx.x];
    __syncthreads();
    int e0 = blockIdx.x * chunk, e1 = min(E, e0 + chunk);
    for (int e = e0 + threadIdx.x; e < e1; e += 1024) {
        int s = ei[e], d = ei[E + e];
        int pos = atomicAdd(&cur[d >> 6], 1);      // LDS atomic
        packed[pos] = (unsigned)s | ((unsigned)(d & 63) << 16);
    }
}

// ---- 5. per-bucket padded CSR: qbeg/qcnt (pair units), dinv, ssrcp --------
// Each node's list starts at an even ushort index and is padded to even
// length with sentinel src = n (zero hs row). Bucket b's region starts at
// pb = even(2 + base[b] + 128*b): 128-slot slack > max 64 pads per bucket.

__global__ __launch_bounds__(1024) void k_csr(const unsigned* __restrict__ packed,
                                              const int* __restrict__ base,
                                              int n,
                                              int* __restrict__ qbeg,
                                              int* __restrict__ qcnt,
                                              float* __restrict__ dinv,
                                              unsigned short* __restrict__ ssrcp,
                                              unsigned short* __restrict__ hs1,
                                              unsigned short* __restrict__ hs2) {
    __shared__ int cnt[64];
    __shared__ int cur[64];
    const int b = blockIdx.x, t = threadIdx.x;
    const int p0 = base[b], p1 = base[b + 1];
    if (t < 64) cnt[t] = 0;
    __syncthreads();
    for (int p = p0 + t; p < p1; p += 1024)
        atomicAdd(&cnt[(packed[p] >> 16) & 63], 1);
    __syncthreads();
    if (t < 64) {                      // wave 0: shuffle scan over padded degs
        int deg = cnt[t];
        int pdeg = (deg + 1) & ~1;     // even-padded degree
        int sum = pdeg;
#pragma unroll
        for (int d = 1; d < 64; d <<= 1) {
            int u = __shfl_up(sum, d, 64);
            if (t >= d) sum += u;
        }
        int excl = sum - pdeg;                       // even
        int pb = (2 + p0 + 128 * b + 1) & ~1;        // even bucket base
        int start = pb + excl;                       // even
        int node = (b << 6) + t;
        if (node < n) {
            qbeg[node] = start >> 1;                 // pair units (>= 1)
            qcnt[node] = pdeg >> 1;
            dinv[node] = 1.0f / sqrtf((float)(deg + 1));  // +1 self-loop
        }
        cur[t] = start;
    }
    __syncthreads();
    for (int p = p0 + t; p < p1; p += 1024) {
        unsigned k = packed[p];
        int pos = atomicAdd(&cur[(k >> 16) & 63], 1);
        ssrcp[pos] = (unsigned short)(k & 0xFFFFu);  // ~4 KB window scatter
    }
    __syncthreads();
    if (t < 64 && (cnt[t] & 1))                      // sentinel pad to even
        ssrcp[cur[t]] = (unsigned short)n;
    if (b == 0) {                                    // zero row n + guard pair
        if (t < 64) {
            hs1[(size_t)n * 64 + t] = 0;
            hs2[(size_t)n * 64 + t] = 0;
        }
        if (t == 0) {
            ssrcp[0] = (unsigned short)n;
            ssrcp[1] = (unsigned short)n;
        }
    }
}

// ---- GEMM: HS[n,64] = bf16( dinv[:,None] * (X[n,K] @ W[K,64]) ) ------------
// Register-tiled: block(256) = 64x64 tile; thread = 4x4. dinv pre-scale fused.

#define FMA4(A, s, wv)                                                         \
    (A).x += (s) * (wv).x; (A).y += (s) * (wv).y;                              \
    (A).z += (s) * (wv).z; (A).w += (s) * (wv).w;

template <int K>
__global__ __launch_bounds__(256) void k_gemm(const float* __restrict__ X,
                                              const float* __restrict__ W,
                                              const float* __restrict__ dinv,
                                              unsigned short* __restrict__ HS,
                                              int n) {
    __shared__ float xl[64][36];
    __shared__ float wl[32][64];

    const int t = threadIdx.x;
    const int tc = t & 15;
    const int tr = t >> 4;
    const int row0 = blockIdx.x * 64;

    float4 acc[4];
    acc[0] = acc[1] = acc[2] = acc[3] = make_float4(0.f, 0.f, 0.f, 0.f);

    for (int k0 = 0; k0 < K; k0 += 32) {
#pragma unroll
        for (int i = 0; i < 2; ++i) {
            int idx = i * 256 + t;
            int r = idx >> 3, f4 = idx & 7;
            int gr = row0 + r;
            float4 v = make_float4(0.f, 0.f, 0.f, 0.f);
            if (gr < n) v = *(const float4*)(X + (size_t)gr * K + k0 + f4 * 4);
            *(float4*)&xl[r][f4 * 4] = v;
        }
#pragma unroll
        for (int i = 0; i < 2; ++i) {
            int idx = i * 256 + t;
            int kr = idx >> 4, f4 = idx & 15;
            *(float4*)&wl[kr][f4 * 4] =
                *(const float4*)(W + (size_t)(k0 + kr) * 64 + f4 * 4);
        }
        __syncthreads();

#pragma unroll
        for (int kk = 0; kk < 32; kk += 4) {
            float4 xv0 = *(float4*)&xl[tr * 4 + 0][kk];
            float4 xv1 = *(float4*)&xl[tr * 4 + 1][kk];
            float4 xv2 = *(float4*)&xl[tr * 4 + 2][kk];
            float4 xv3 = *(float4*)&xl[tr * 4 + 3][kk];
            float4 wv0 = *(float4*)&wl[kk + 0][tc * 4];
            float4 wv1 = *(float4*)&wl[kk + 1][tc * 4];
            float4 wv2 = *(float4*)&wl[kk + 2][tc * 4];
            float4 wv3 = *(float4*)&wl[kk + 3][tc * 4];

            FMA4(acc[0], xv0.x, wv0); FMA4(acc[0], xv0.y, wv1);
            FMA4(acc[0], xv0.z, wv2); FMA4(acc[0], xv0.w, wv3);
            FMA4(acc[1], xv1.x, wv0); FMA4(acc[1], xv1.y, wv1);
            FMA4(acc[1], xv1.z, wv2); FMA4(acc[1], xv1.w, wv3);
            FMA4(acc[2], xv2.x, wv0); FMA4(acc[2], xv2.y, wv1);
            FMA4(acc[2], xv2.z, wv2); FMA4(acc[2], xv2.w, wv3);
            FMA4(acc[3], xv3.x, wv0); FMA4(acc[3], xv3.y, wv1);
            FMA4(acc[3], xv3.z, wv2); FMA4(acc[3], xv3.w, wv3);
        }
        __syncthreads();
    }

#pragma unroll
    for (int ri = 0; ri < 4; ++ri) {
        int gr = row0 + tr * 4 + ri;
        if (gr < n) {
            float dv = dinv[gr];
            float4 o = acc[ri];
            ushort4 pk;
            pk.x = f2bf(o.x * dv); pk.y = f2bf(o.y * dv);
            pk.z = f2bf(o.z * dv); pk.w = f2bf(o.w * dv);
            *(ushort4*)(HS + (size_t)gr * 64 + tc * 4) = pk;
        }
    }
}

// ---- 6. aggregation: out[i] = dinv[i]*(sum_src hs[src] + hs[i]) + b -------
// Wave per node. dwordx4 gathers: one instr = 64 lanes x 16B = 8 edge-rows
// (lane -> edge g = lane>>3, channel octet c = lane&7). 8-pair batches,
// all pairs live (sentinel padding) so NO masks; full batches use
// consecutive scalar index loads (s_load_dwordx8); tail batch selects dead
// slots to guard pair 0 via SALU cselect. 3-level xor-shuffle edge reduce.

template <bool RELU>
__global__ __launch_bounds__(256) void k_agg(const unsigned short* __restrict__ hs,  // n+1 rows
                      const int* __restrict__ qbeg,
                      const int* __restrict__ qcnt,
                      const unsigned short* __restrict__ ssrcp,
                      const float* __restrict__ dinv,
                      const float* __restrict__ bias,
                      float* __restrict__ out, int n) {
    int node = blockIdx.x * 4 + (threadIdx.x >> 6);
    if (node >= n) return;
    node = __builtin_amdgcn_readfirstlane(node);   // SGPR -> scalar loads
    const int lane = threadIdx.x & 63;
    const int c = lane & 7;               // channel octet: ch 8c..8c+7
    const int shH = (lane & 8) ? 16 : 0;  // pair half of edge g = lane>>3

    const uint4* hs4 = (const uint4*)hs;           // row = 8 uint4 (128 B)
    const unsigned* ssu = (const unsigned*)ssrcp;  // src pairs

    const int q0 = qbeg[node];
    const int m  = qcnt[node];

    // epilogue operands issued early, in flight during the gather loop
    const uint4 sv = hs4[node * 8 + c];
    const float dv = dinv[node];
    const float4 bv0 = *(const float4*)(bias + 8 * c);
    const float4 bv1 = *(const float4*)(bias + 8 * c + 4);

    float ax[8];
#pragma unroll
    for (int k = 0; k < 8; ++k) ax[k] = 0.f;

    int qb = 0;
    for (; qb + 8 <= m; qb += 8) {                 // full batches: no selects
        unsigned ssl[8];
#pragma unroll
        for (int j = 0; j < 8; ++j) ssl[j] = ssu[q0 + qb + j];
        uint4 v[2];
#pragma unroll
        for (int i = 0; i < 2; ++i) {              // instr i covers pairs 4i..4i+3
            unsigned w = (lane & 32) ? ((lane & 16) ? ssl[4 * i + 3] : ssl[4 * i + 2])
                                     : ((lane & 16) ? ssl[4 * i + 1] : ssl[4 * i + 0]);
            int s = (int)((w >> shH) & 0xFFFFu);
            v[i] = hs4[s * 8 + c];
        }
#pragma unroll
        for (int i = 0; i < 2; ++i) {
            ax[0] += blo(v[i].x); ax[1] += bhi(v[i].x);
            ax[2] += blo(v[i].y); ax[3] += bhi(v[i].y);
            ax[4] += blo(v[i].z); ax[5] += bhi(v[i].z);
            ax[6] += blo(v[i].w); ax[7] += bhi(v[i].w);
        }
    }
    const int rem = m - qb;
    if (rem) {                                     // one tail batch, SALU sel
        unsigned ssl[8];
#pragma unroll
        for (int j = 0; j < 8; ++j) {
            int q = (j < rem) ? (q0 + qb + j) : 0; // 0 = {n,n} guard pair
            ssl[j] = ssu[q];
        }
        uint4 v[2];
#pragma unroll
        for (int i = 0; i < 2; ++i) {
            unsigned w = (lane & 32) ? ((lane & 16) ? ssl[4 * i + 3] : ssl[4 * i + 2])
                                     : ((lane & 16) ? ssl[4 * i + 1] : ssl[4 * i + 0]);
            int s = (int)((w >> shH) & 0xFFFFu);
            v[i] = hs4[s * 8 + c];
        }
#pragma unroll
        for (int i = 0; i < 2; ++i) {
            ax[0] += blo(v[i].x); ax[1] += bhi(v[i].x);
            ax[2] += blo(v[i].y); ax[3] += bhi(v[i].y);
            ax[4] += blo(v[i].z); ax[5] += bhi(v[i].z);
            ax[6] += blo(v[i].w); ax[7] += bhi(v[i].w);
        }
    }

    // reduce over the 8 edge slots (lane bits 3..5); channels (bits 0..2) kept
#pragma unroll
    for (int k = 0; k < 8; ++k) {
        ax[k] += __shfl_xor(ax[k], 8, 64);
        ax[k] += __shfl_xor(ax[k], 16, 64);
        ax[k] += __shfl_xor(ax[k], 32, 64);
    }

    // epilogue: self-loop + scale + bias (+ relu); lanes 0..15 store 256 B
    float r[8];
    r[0] = dv * (ax[0] + blo(sv.x)) + bv0.x;
    r[1] = dv * (ax[1] + bhi(sv.x)) + bv0.y;
    r[2] = dv * (ax[2] + blo(sv.y)) + bv0.z;
    r[3] = dv * (ax[3] + bhi(sv.y)) + bv0.w;
    r[4] = dv * (ax[4] + blo(sv.z)) + bv1.x;
    r[5] = dv * (ax[5] + bhi(sv.z)) + bv1.y;
    r[6] = dv * (ax[6] + blo(sv.w)) + bv1.z;
    r[7] = dv * (ax[7] + bhi(sv.w)) + bv1.w;
    if (RELU) {
#pragma unroll
        for (int k = 0; k < 8; ++k) r[k] = fmaxf(r[k], 0.f);
    }
    if (lane < 16) {
        float4 o = (lane & 8) ? make_float4(r[4], r[5], r[6], r[7])
                              : make_float4(r[0], r[1], r[2], r[3]);
        *(float4*)(out + (size_t)node * 64 + 8 * c + 4 * ((lane >> 3) & 1)) = o;
    }
}

// ---- launch ----------------------------------------------------------------

extern "C" void kernel_launch(void* const* d_in, const int* in_sizes, int n_in,
                              void* d_out, int out_size, void* d_ws, size_t ws_size,
                              hipStream_t stream) {
    const float* x  = (const float*)d_in[0];
    const int*   ei = (const int*)d_in[1];
    const float* W1 = (const float*)d_in[2];
    const float* b1 = (const float*)d_in[3];
    const float* W2 = (const float*)d_in[4];
    const float* b2 = (const float*)d_in[5];

    const int n = in_sizes[0] / 256;   // 50000 (< 65536: ushort src packing)
    const int E = in_sizes[1] / 2;     // 1600000
    const int nb = (n + 63) >> 6;      // 782 buckets
    const int chunk = (E + 255) / 256;

    // workspace carve-up (256B aligned)
    char* ws = (char*)d_ws;
    auto carve = [&](size_t bytes) {
        void* p = (void*)ws;
        ws += (bytes + 255) & ~(size_t)255;
        return p;
    };
    int*            histT  = (int*)carve((size_t)nb * 256 * 4);
    int*            total  = (int*)carve((size_t)nb * 4);
    int*            base   = (int*)carve((size_t)(nb + 1) * 4);
    unsigned*       packed = (unsigned*)carve((size_t)E * 4);
    unsigned short* ssrcp  = (unsigned short*)carve(((size_t)E + 128 * nb + 256) * 2);
    int*            qbeg   = (int*)carve((size_t)n * 4);
    int*            qcnt   = (int*)carve((size_t)n * 4);
    float*          dinv   = (float*)carve((size_t)n * 4);
    unsigned short* hs1    = (unsigned short*)carve((size_t)(n + 1) * 64 * 2);
    float*          hB     = (float*)carve((size_t)n * 64 * 4);
    unsigned short* hs2    = (unsigned short*)carve((size_t)(n + 1) * 64 * 2);

    k_hist<<<256, 1024, 0, stream>>>(ei, E, nb, chunk, histT);
    k_scan_cols<<<nb, 256, 0, stream>>>(histT, total);
    k_scan_totals<<<1, 1024, 0, stream>>>(total, base, nb);
    k_scatter<<<256, 1024, 0, stream>>>(ei, E, nb, chunk, histT, base, packed);
    k_csr<<<nb, 1024, 0, stream>>>(packed, base, n, qbeg, qcnt, dinv, ssrcp,
                                   hs1, hs2);

    const int nbG = (n + 63) / 64;

    // layer 1: hs1 = bf16(dinv*(x@W1)) ; hB = relu(agg + b1)
    k_gemm<256><<<nbG, 256, 0, stream>>>(x, W1, dinv, hs1, n);
    k_agg<true><<<(n + 3) / 4, 256, 0, stream>>>(hs1, qbeg, qcnt, ssrcp, dinv,
                                                 b1, hB, n);

    // layer 2: hs2 = bf16(dinv*(hB@W2)) ; out = agg + b2
    k_gemm<64><<<nbG, 256, 0, stream>>>(hB, W2, dinv, hs2, n);
    k_agg<false><<<(n + 3) / 4, 256, 0, stream>>>(hs2, qbeg, qcnt, ssrcp, dinv,
                                                  b2, (float*)d_out, n);
}